// Round 10
// baseline (100.360 us; speedup 1.0000x reference)
//
#include <hip/hip_runtime.h>
#include <math.h>

#define NN    8192
#define CIN   256
#define COUT  128
#define MAXEG 256      // max edges kept per row (mean ~82, sigma ~9 -> 19 sigma)
#define NK1   512      // GEMM blocks
#define NBM   512      // bitmap blocks: 512 blocks x 4 waves = 2048 streams,
                       // each wave owns a contiguous 128 KB of adj

typedef unsigned uvec4 __attribute__((ext_vector_type(4)));

// ---------------------------------------------------------------------------
// Kernel A: bid < NK1  -> GEMM: h = X@W + b ; f1 = h@v0 ; f2 = h@v1
//           bid >= NK1 -> adjacency -> bitmap, few-deep-streams structure.
// Bitmap byte u covers adj elements [8u, 8u+8), bit b = element 8u+b.
// ---------------------------------------------------------------------------
__global__ __launch_bounds__(256) void kAB(
    const float* __restrict__ X, const float* __restrict__ adj,
    const float* __restrict__ W, const float* __restrict__ b,
    const float* __restrict__ v0, const float* __restrict__ v1,
    float* __restrict__ h, float* __restrict__ f1, float* __restrict__ f2,
    unsigned char* __restrict__ bm)
{
    const int tid = threadIdx.x;

    if (blockIdx.x < NK1) {
        // ---------------- GEMM ----------------
        __shared__ float Xs[16][32];
        const int ct  = tid & 63;
        const int rg  = tid >> 6;
        const int c   = ct * 2;
        const int row0 = blockIdx.x * 16;

        float acc[4][2] = {{0.f,0.f},{0.f,0.f},{0.f,0.f},{0.f,0.f}};

        for (int kc = 0; kc < CIN; kc += 32) {
            if (tid < 128) {
                const int r = tid >> 3, q = tid & 7;
                const float4 xv = *(const float4*)(X + (size_t)(row0 + r) * CIN + kc + q * 4);
                *(float4*)&Xs[r][q * 4] = xv;
            }
            float2 wv[32];
            #pragma unroll
            for (int kk = 0; kk < 32; ++kk)
                wv[kk] = *(const float2*)(W + (size_t)(kc + kk) * COUT + c);
            __syncthreads();

            #pragma unroll
            for (int rr = 0; rr < 4; ++rr) {
                const int lr = rg * 4 + rr;
                #pragma unroll
                for (int k4 = 0; k4 < 8; ++k4) {
                    const float4 xv = *(const float4*)&Xs[lr][k4 * 4];
                    acc[rr][0] += xv.x * wv[k4*4+0].x; acc[rr][1] += xv.x * wv[k4*4+0].y;
                    acc[rr][0] += xv.y * wv[k4*4+1].x; acc[rr][1] += xv.y * wv[k4*4+1].y;
                    acc[rr][0] += xv.z * wv[k4*4+2].x; acc[rr][1] += xv.z * wv[k4*4+2].y;
                    acc[rr][0] += xv.w * wv[k4*4+3].x; acc[rr][1] += xv.w * wv[k4*4+3].y;
                }
            }
            __syncthreads();
        }

        const float b0 = b[c], b1 = b[c+1];
        const float v00 = v0[c], v01 = v0[c+1];
        const float v10 = v1[c], v11 = v1[c+1];

        #pragma unroll
        for (int rr = 0; rr < 4; ++rr) {
            const int row = row0 + rg * 4 + rr;
            const float h0 = acc[rr][0] + b0;
            const float h1 = acc[rr][1] + b1;
            *(float2*)(h + (size_t)row * COUT + c) = make_float2(h0, h1);
            float p0 = h0 * v00 + h1 * v01;
            float p1 = h0 * v10 + h1 * v11;
            #pragma unroll
            for (int off = 32; off; off >>= 1) {
                p0 += __shfl_down(p0, off, 64);
                p1 += __shfl_down(p1, off, 64);
            }
            if (ct == 0) { f1[row] = p0; f2[row] = p1; }
        }
    } else {
        // ---------------- bitmap: wave-contiguous deep stream ----------------
        const int bb   = blockIdx.x - NK1;
        const int wid  = tid >> 6;
        const int lane = tid & 63;
        // wave stream id in [0, 2048): owns contiguous 128 KB = 8192 uvec4
        const int ws   = bb * 4 + wid;
        const uvec4* wp = (const uvec4*)adj + (size_t)ws * 8192 + lane * 2;
        unsigned char* bp = bm + (size_t)ws * 4096 + lane;

        #pragma unroll 8
        for (int i = 0; i < 64; ++i) {
            const uvec4 a = __builtin_nontemporal_load(wp + i * 128);
            const uvec4 d = __builtin_nontemporal_load(wp + i * 128 + 1);
            const unsigned m =
                (a.x ? 1u  : 0u) | (a.y ? 2u  : 0u) | (a.z ? 4u  : 0u) | (a.w ? 8u   : 0u) |
                (d.x ? 16u : 0u) | (d.y ? 32u : 0u) | (d.z ? 64u : 0u) | (d.w ? 128u : 0u);
            bp[i * 64] = (unsigned char)m;
        }
    }
}

// ---------------------------------------------------------------------------
// Phase 2: wave-per-row. Decode bitmap row (16 B/lane = 128 elems) ->
// prefix-sum compact edge list into LDS -> softmax -> 8-deep L2 gather of h.
// ---------------------------------------------------------------------------
__global__ __launch_bounds__(256) void k2_attn(
    const unsigned* __restrict__ bm, const float* __restrict__ h,
    const float* __restrict__ f1, const float* __restrict__ f2,
    float* __restrict__ out)
{
    __shared__ unsigned short sjl[4][MAXEG];
    __shared__ float vl[4][MAXEG];

    const int tid  = threadIdx.x;
    const int wid  = tid >> 6;
    const int lane = tid & 63;
    const int row  = blockIdx.x * 4 + wid;
    const int c    = lane * 2;

    // bitmap row = 1 KB; lane reads 16 B covering elems [lane*128, lane*128+128)
    const uvec4 w4 = ((const uvec4*)(bm + (size_t)row * 256))[lane];
    unsigned wa[4] = { w4.x, w4.y, w4.z, w4.w };

    const int lc = __popc(wa[0]) + __popc(wa[1]) + __popc(wa[2]) + __popc(wa[3]);
    int pre = lc;
    #pragma unroll
    for (int off = 1; off < 64; off <<= 1) {
        const int t = __shfl_up(pre, off, 64);
        if (lane >= off) pre += t;
    }
    unsigned p = (unsigned)(pre - lc);
    const int n0 = __shfl(pre, 63, 64);
    const int n  = min(n0, MAXEG);

    const int jb = lane * 128;
    #pragma unroll
    for (int k = 0; k < 4; ++k) {
        unsigned mm = wa[k];
        while (mm) {
            const int bit = __builtin_ctz(mm);
            mm &= mm - 1;
            if (p < MAXEG) sjl[wid][p] = (unsigned short)(jb + k * 32 + bit);
            ++p;
        }
    }

    if (n == 0) {   // wave-uniform exit
        *(float2*)(out + (size_t)row * COUT + c) = make_float2(0.f, 0.f);
        return;
    }
    asm volatile("s_waitcnt lgkmcnt(0)" ::: "memory");

    // ---- softmax over n <= 256 edges ----
    const float f1i = f1[row];
    float m = -1e30f;
    #pragma unroll
    for (int q = 0; q < 4; ++q) {
        const int pp = lane + q * 64;
        if (pp < n) {
            const float x = f1i + f2[sjl[wid][pp]];
            const float s = 1.f / (1.f + __expf(-x)) - 0.5f;
            vl[wid][pp] = s;
            m = fmaxf(m, s);
        }
    }
    #pragma unroll
    for (int off = 32; off; off >>= 1) m = fmaxf(m, __shfl_xor(m, off, 64));

    float ssum = 0.f;
    #pragma unroll
    for (int q = 0; q < 4; ++q) {
        const int pp = lane + q * 64;
        if (pp < n) {
            const float e = __expf(vl[wid][pp] - m);
            vl[wid][pp] = e;
            ssum += e;
        }
    }
    #pragma unroll
    for (int off = 32; off; off >>= 1) ssum += __shfl_xor(ssum, off, 64);
    const float inv = 1.f / ssum;
    asm volatile("s_waitcnt lgkmcnt(0)" ::: "memory");

    // ---- weighted gather of h rows: lane owns cols [2l,2l+1], 8-deep ILP ----
    float ax = 0.f, ay = 0.f;
    int q = 0;
    for (; q + 7 < n; q += 8) {
        int   jj[8];
        float ww[8];
        float2 aa[8];
        #pragma unroll
        for (int u = 0; u < 8; ++u) { jj[u] = sjl[wid][q + u]; ww[u] = vl[wid][q + u]; }
        #pragma unroll
        for (int u = 0; u < 8; ++u) aa[u] = *(const float2*)(h + (size_t)jj[u] * COUT + c);
        #pragma unroll
        for (int u = 0; u < 8; ++u) { ax += ww[u] * aa[u].x; ay += ww[u] * aa[u].y; }
    }
    for (; q < n; ++q) {
        const int   j = sjl[wid][q];
        const float w = vl[wid][q];
        const float2 a = *(const float2*)(h + (size_t)j * COUT + c);
        ax += w * a.x;
        ay += w * a.y;
    }
    *(float2*)(out + (size_t)row * COUT + c) = make_float2(ax * inv, ay * inv);
}

extern "C" void kernel_launch(void* const* d_in, const int* in_sizes, int n_in,
                              void* d_out, int out_size, void* d_ws, size_t ws_size,
                              hipStream_t stream) {
    const float* X   = (const float*)d_in[0];
    const float* adj = (const float*)d_in[1];
    const float* W   = (const float*)d_in[2];
    const float* b   = (const float*)d_in[3];
    const float* v0  = (const float*)d_in[4];
    const float* v1  = (const float*)d_in[5];
    float* out = (float*)d_out;

    float*         h  = (float*)d_ws;                  // 8192*128 f32 = 4 MB
    float*         f1 = h + (size_t)NN * COUT;         // 32 KB
    float*         f2 = f1 + NN;                       // 32 KB
    unsigned char* bm = (unsigned char*)(f2 + NN);     // 8 MB bitmap

    kAB<<<NK1 + NBM, 256, 0, stream>>>(X, adj, W, b, v0, v1, h, f1, f2, bm);
    k2_attn<<<NN / 4, 256, 0, stream>>>((const unsigned*)bm, h, f1, f2, out);
}

// Round 11
// 88.829 us; speedup vs baseline: 1.1298x; 1.1298x over previous
//
#include <hip/hip_runtime.h>
#include <math.h>

#define NN    8192
#define CIN   256
#define COUT  128
#define NK1   512      // k1 GEMM blocks (16 rows each)
#define MAXEG 256      // max edges stored per row (mean ~82, sigma ~9 -> 19 sigma)

typedef unsigned uvec4 __attribute__((ext_vector_type(4)));

// ---------------------------------------------------------------------------
// Kernel A (R4-verbatim): blockIdx < NK1  -> GEMM (h = X@W + b, f1, f2)
//                         blockIdx >= NK1 -> adjacency row scan -> u16 list.
// Edge list for row i lives in d_out row i (512 B); kB consumes then
// overwrites it (same wave reads before writing -> no hazard).
// ---------------------------------------------------------------------------
__global__ __launch_bounds__(256) void kA(
    const float* __restrict__ X, const float* __restrict__ adj,
    const float* __restrict__ W, const float* __restrict__ b,
    const float* __restrict__ v0, const float* __restrict__ v1,
    float* __restrict__ h, float* __restrict__ f1, float* __restrict__ f2,
    unsigned* __restrict__ cnt, unsigned* __restrict__ outw)
{
    __shared__ float Xs[16][32];
    __shared__ unsigned scnt;
    __shared__ unsigned short sjl[MAXEG];

    const int tid = threadIdx.x;

    if (blockIdx.x < NK1) {
        // ---------------- GEMM ----------------
        const int ct  = tid & 63;
        const int rg  = tid >> 6;
        const int c   = ct * 2;
        const int row0 = blockIdx.x * 16;

        float acc[4][2] = {{0.f,0.f},{0.f,0.f},{0.f,0.f},{0.f,0.f}};

        for (int kc = 0; kc < CIN; kc += 32) {
            if (tid < 128) {
                const int r = tid >> 3, q = tid & 7;
                const float4 xv = *(const float4*)(X + (size_t)(row0 + r) * CIN + kc + q * 4);
                *(float4*)&Xs[r][q * 4] = xv;
            }
            float2 wv[32];
            #pragma unroll
            for (int kk = 0; kk < 32; ++kk)
                wv[kk] = *(const float2*)(W + (size_t)(kc + kk) * COUT + c);
            __syncthreads();

            #pragma unroll
            for (int rr = 0; rr < 4; ++rr) {
                const int lr = rg * 4 + rr;
                #pragma unroll
                for (int k4 = 0; k4 < 8; ++k4) {
                    const float4 xv = *(const float4*)&Xs[lr][k4 * 4];
                    acc[rr][0] += xv.x * wv[k4*4+0].x; acc[rr][1] += xv.x * wv[k4*4+0].y;
                    acc[rr][0] += xv.y * wv[k4*4+1].x; acc[rr][1] += xv.y * wv[k4*4+1].y;
                    acc[rr][0] += xv.z * wv[k4*4+2].x; acc[rr][1] += xv.z * wv[k4*4+2].y;
                    acc[rr][0] += xv.w * wv[k4*4+3].x; acc[rr][1] += xv.w * wv[k4*4+3].y;
                }
            }
            __syncthreads();
        }

        const float b0 = b[c], b1 = b[c+1];
        const float v00 = v0[c], v01 = v0[c+1];
        const float v10 = v1[c], v11 = v1[c+1];

        #pragma unroll
        for (int rr = 0; rr < 4; ++rr) {
            const int row = row0 + rg * 4 + rr;
            const float h0 = acc[rr][0] + b0;
            const float h1 = acc[rr][1] + b1;
            *(float2*)(h + (size_t)row * COUT + c) = make_float2(h0, h1);
            float p0 = h0 * v00 + h1 * v01;
            float p1 = h0 * v10 + h1 * v11;
            #pragma unroll
            for (int off = 32; off; off >>= 1) {
                p0 += __shfl_down(p0, off, 64);
                p1 += __shfl_down(p1, off, 64);
            }
            if (ct == 0) { f1[row] = p0; f2[row] = p1; }
        }
    } else {
        // ---------------- scan: stream + compact (R4 structure) ----------------
        const int i = blockIdx.x - NK1;
        const uvec4* rowp = (const uvec4*)(adj + (size_t)i * NN);
        uvec4 v[8];
        #pragma unroll
        for (int it = 0; it < 8; ++it)
            v[it] = __builtin_nontemporal_load(rowp + tid + it * 256);

        if (tid == 0) scnt = 0;
        __syncthreads();

        #pragma unroll
        for (int it = 0; it < 8; ++it) {
            if (v[it].x | v[it].y | v[it].z | v[it].w) {
                const int j0 = (tid + it * 256) * 4;
                if (v[it].x) { const unsigned p = atomicAdd(&scnt, 1u); if (p < MAXEG) sjl[p] = (unsigned short)(j0    ); }
                if (v[it].y) { const unsigned p = atomicAdd(&scnt, 1u); if (p < MAXEG) sjl[p] = (unsigned short)(j0 + 1); }
                if (v[it].z) { const unsigned p = atomicAdd(&scnt, 1u); if (p < MAXEG) sjl[p] = (unsigned short)(j0 + 2); }
                if (v[it].w) { const unsigned p = atomicAdd(&scnt, 1u); if (p < MAXEG) sjl[p] = (unsigned short)(j0 + 3); }
            }
        }
        __syncthreads();

        if (tid < 128) {
            const unsigned w = (unsigned)sjl[2 * tid] | ((unsigned)sjl[2 * tid + 1] << 16);
            outw[(size_t)i * 128 + tid] = w;    // packed edge list lives in out row i
        }
        if (tid == 0) cnt[i] = min(scnt, (unsigned)MAXEG);
    }
}

// ---------------------------------------------------------------------------
// Kernel B (R6-verbatim): wave-per-row softmax + gather. No block barriers.
// Reads packed edge list from out row i, overwrites out row i at the end.
// ---------------------------------------------------------------------------
__global__ __launch_bounds__(256) void kB(
    const float* __restrict__ h, const float* __restrict__ f1,
    const float* __restrict__ f2, const unsigned* __restrict__ cnt,
    float* __restrict__ out)
{
    __shared__ unsigned short jl[4][MAXEG];
    __shared__ float vl[4][MAXEG];
    const int tid  = threadIdx.x;
    const int wid  = tid >> 6;
    const int lane = tid & 63;
    const int i    = blockIdx.x * 4 + wid;
    const int n    = (int)cnt[i];
    const int c    = lane * 2;

    if (n == 0) {
        *(float2*)(out + (size_t)i * COUT + c) = make_float2(0.f, 0.f);
        return;   // wave-uniform exit
    }

    #pragma unroll
    for (int r = 0; r < 2; ++r) {
        const int k = lane + r * 64;
        const unsigned w = ((const unsigned*)out)[(size_t)i * 128 + k];
        jl[wid][2 * k]     = (unsigned short)(w & 0xffffu);
        jl[wid][2 * k + 1] = (unsigned short)(w >> 16);
    }
    asm volatile("s_waitcnt lgkmcnt(0)" ::: "memory");

    const float f1i = f1[i];
    float m = -1e30f;
    #pragma unroll
    for (int q = 0; q < 4; ++q) {
        const int p = lane + q * 64;
        if (p < n) {
            const float x = f1i + f2[jl[wid][p]];
            const float s = 1.f / (1.f + __expf(-x)) - 0.5f;
            vl[wid][p] = s;
            m = fmaxf(m, s);
        }
    }
    #pragma unroll
    for (int off = 32; off; off >>= 1) m = fmaxf(m, __shfl_xor(m, off, 64));

    float ssum = 0.f;
    #pragma unroll
    for (int q = 0; q < 4; ++q) {
        const int p = lane + q * 64;
        if (p < n) {
            const float e = __expf(vl[wid][p] - m);
            vl[wid][p] = e;
            ssum += e;
        }
    }
    #pragma unroll
    for (int off = 32; off; off >>= 1) ssum += __shfl_xor(ssum, off, 64);
    const float inv = 1.f / ssum;
    asm volatile("s_waitcnt lgkmcnt(0)" ::: "memory");

    // weighted gather: lane owns cols [2l,2l+1]; 4-deep unroll over edges.
    float ax = 0.f, ay = 0.f;
    int p = 0;
    for (; p + 3 < n; p += 4) {
        const int   j0 = jl[wid][p],     j1 = jl[wid][p + 1];
        const int   j2 = jl[wid][p + 2], j3 = jl[wid][p + 3];
        const float w0 = vl[wid][p],     w1 = vl[wid][p + 1];
        const float w2 = vl[wid][p + 2], w3 = vl[wid][p + 3];
        const float2 a0 = *(const float2*)(h + (size_t)j0 * COUT + c);
        const float2 a1 = *(const float2*)(h + (size_t)j1 * COUT + c);
        const float2 a2 = *(const float2*)(h + (size_t)j2 * COUT + c);
        const float2 a3 = *(const float2*)(h + (size_t)j3 * COUT + c);
        ax += w0 * a0.x + w1 * a1.x + w2 * a2.x + w3 * a3.x;
        ay += w0 * a0.y + w1 * a1.y + w2 * a2.y + w3 * a3.y;
    }
    for (; p < n; ++p) {
        const int   j = jl[wid][p];
        const float w = vl[wid][p];
        const float2 a = *(const float2*)(h + (size_t)j * COUT + c);
        ax += w * a.x;
        ay += w * a.y;
    }
    *(float2*)(out + (size_t)i * COUT + c) = make_float2(ax * inv, ay * inv);
}

extern "C" void kernel_launch(void* const* d_in, const int* in_sizes, int n_in,
                              void* d_out, int out_size, void* d_ws, size_t ws_size,
                              hipStream_t stream) {
    const float* X   = (const float*)d_in[0];
    const float* adj = (const float*)d_in[1];
    const float* W   = (const float*)d_in[2];
    const float* b   = (const float*)d_in[3];
    const float* v0  = (const float*)d_in[4];
    const float* v1  = (const float*)d_in[5];
    float* out = (float*)d_out;

    float*    h   = (float*)d_ws;                  // 8192*128 f32 = 4 MB
    float*    f1  = h + (size_t)NN * COUT;         // 32 KB
    float*    f2  = f1 + NN;                       // 32 KB
    unsigned* cnt = (unsigned*)(f2 + NN);          // 32 KB

    kA<<<NK1 + NN, 256, 0, stream>>>(X, adj, W, b, v0, v1, h, f1, f2, cnt, (unsigned*)out);
    kB<<<NN / 4, 256, 0, stream>>>(h, f1, f2, cnt, out);
}